// Round 3
// baseline (2132.121 us; speedup 1.0000x reference)
//
#include <hip/hip_runtime.h>
#include <stdint.h>

// ---- problem constants ----
#define WIN_N 49
#define NH 16
#define HD 32
#define CDIM 512
#define NB 4096
#define M_ROWS (NB * WIN_N)        // 200704 = 128 * 1568 exactly
#define QKV_N 1536
#define SCALE_Q 0.17677669529663689f  // 32^-0.5

typedef __attribute__((ext_vector_type(8))) short bf16x8;
typedef __attribute__((ext_vector_type(4))) float f32x4;

__device__ __forceinline__ unsigned short f2bf(float f) {
  unsigned int u = __float_as_uint(f);
  u += 0x7fff + ((u >> 16) & 1);   // RNE
  return (unsigned short)(u >> 16);
}
__device__ __forceinline__ unsigned int pack2(float a, float b) {
  return (unsigned int)f2bf(a) | ((unsigned int)f2bf(b) << 16);
}

// global->LDS direct DMA, 16B/lane. LDS dest is wave-uniform base + lane*16
// (m97/m104 semantics); global src is per-lane.
typedef const __attribute__((address_space(1))) unsigned int* gas1_t;
typedef __attribute__((address_space(3))) unsigned int* las3_t;
#define GL2LDS(g, l) __builtin_amdgcn_global_load_lds((gas1_t)(g), (las3_t)(l), 16, 0, 0)

// counted vmcnt wait (T4): compile-time constant N, "memory" clobber blocks
// compiler code-motion of any memory op across it.
#define VMW(n) asm volatile("s_waitcnt vmcnt(" #n ")" ::: "memory")
// raw barrier (does NOT drain vmcnt, unlike __syncthreads) + scheduling fence
// so ds_reads can't be hoisted above it (rule #18 analog).
#define BAR()                                   \
  do {                                          \
    __builtin_amdgcn_s_barrier();               \
    __builtin_amdgcn_sched_barrier(0);          \
    asm volatile("" ::: "memory");              \
  } while (0)

// ---- kernel 1: transpose + bf16-convert weights: wT[n][k] = w[k][n] ----
__global__ void prep_weights(const float* __restrict__ qkv_w,
                             const float* __restrict__ proj_w,
                             unsigned short* __restrict__ wqkv_t,
                             unsigned short* __restrict__ wproj_t) {
  int i = blockIdx.x * blockDim.x + threadIdx.x;
  if (i < QKV_N * CDIM) {                 // 786432: [1536][512]
    int n = i >> 9, k = i & 511;
    wqkv_t[i] = f2bf(qkv_w[k * QKV_N + n]);
  } else {
    int j = i - QKV_N * CDIM;
    if (j < CDIM * CDIM) {                // 262144: [512][512]
      int n = j >> 9, k = j & 511;
      wproj_t[j] = f2bf(proj_w[k * CDIM + n]);
    }
  }
}

// ---- kernel 1b: x (f32) -> xb (bf16), one pass, memory-bound ----
__global__ void conv_x(const float* __restrict__ x,
                       unsigned short* __restrict__ xb, int n8) {
  int i = blockIdx.x * blockDim.x + threadIdx.x;
  const int stride = gridDim.x * blockDim.x;
  for (; i < n8; i += stride) {
    const float4* p = (const float4*)(x + (size_t)i * 8);
    float4 a = p[0], b = p[1];
    *(uint4*)(xb + (size_t)i * 8) =
        make_uint4(pack2(a.x, a.y), pack2(a.z, a.w), pack2(b.x, b.y), pack2(b.z, b.w));
  }
}

// ---- kernel 2/4: C[M][N] = A[M][K] * Bt[N][K]^T, 128x128 tile, BK=32 ----
// Ring-4 pipeline (T3+T4): 4 LDS buffers; stage tile t+3 while computing t;
// per-tile sync = s_waitcnt vmcnt(8) + raw s_barrier -> 8 loads (2 tiles)
// stay in flight across every barrier; drain 8->4->0 only in the 3-iter tail.
//
// LDS tile layout is CHUNK-MAJOR: element (row, k=c*8+u) at ushort index
// c*1024 + row*8 + u  (c=0..3, row=0..127). Staging thread t writes linear
// bytes t*16 (gl2lds uniform-base+lane*16), which equals (c=t>>7, row=t&127)
// for issue 0 and c+2 for issue 1 -> both sides agree (rule #21, trivially).
// Frag read for (row, quad): ushort idx quad*1024 + row*8 -> lanes stride
// 16B -> 2-way bank aliasing = free (m136), vs 8-way in the row-major layout.
template <bool OUT_F32>
__global__ __launch_bounds__(256, 2) void gemm_bt(
    const unsigned short* __restrict__ A, int lda,
    const unsigned short* __restrict__ Bt,
    void* __restrict__ Cptr, int ldc,
    const float* __restrict__ bias,
    int K, int scale_cols, float scale) {
  __shared__ __align__(16) unsigned short As[4][4096];  // 4 x 8KB
  __shared__ __align__(16) unsigned short Bs[4][4096];  // 4 x 8KB  (total 64KB)
  const int tid = threadIdx.x;

  // T1: XCD-chunked bijective block swizzle (nwg % 8 == 0 at both call sites).
  const int gx = gridDim.x;
  const int nwg = gx * gridDim.y;
  int lin = blockIdx.y * gx + blockIdx.x;
  lin = (lin & 7) * (nwg >> 3) + (lin >> 3);
  const int bm = (lin / gx) * 128;
  const int bn = (lin % gx) * 128;

  const int lane = tid & 63, wid = tid >> 6;
  const int wm = (wid & 1) * 64, wn = (wid >> 1) * 64;
  const int quad = lane >> 4, l16 = lane & 15;

  const f32x4 fzero = {0.f, 0.f, 0.f, 0.f};
  f32x4 acc[4][4];
#pragma unroll
  for (int i = 0; i < 4; i++)
#pragma unroll
    for (int j = 0; j < 4; j++) acc[i][j] = fzero;

  // staging source: thread t covers (row = t&127, k-chunk = t>>7) and chunk+2
  const int rS = tid & 127;
  const int cS = (tid >> 7) * 8;
  const unsigned short* pA0 = A + (size_t)(bm + rS) * lda + cS;
  const unsigned short* pB0 = Bt + (size_t)(bn + rS) * K + cS;

#define STAGE(bb, kk_)                                    \
  do {                                                    \
    GL2LDS(pA0 + (kk_), &As[bb][wid * 512]);              \
    GL2LDS(pA0 + (kk_) + 16, &As[bb][2048 + wid * 512]);  \
    GL2LDS(pB0 + (kk_), &Bs[bb][wid * 512]);              \
    GL2LDS(pB0 + (kk_) + 16, &Bs[bb][2048 + wid * 512]);  \
  } while (0)

#define COMPUTE(bb)                                                              \
  do {                                                                           \
    const unsigned short* Ab = &As[bb][quad * 1024];                             \
    const unsigned short* Bb = &Bs[bb][quad * 1024];                             \
    bf16x8 a[4], b[4];                                                           \
    _Pragma("unroll") for (int i = 0; i < 4; i++)                                \
        a[i] = *(const bf16x8*)&Ab[(wm + i * 16 + l16) * 8];                     \
    _Pragma("unroll") for (int i = 0; i < 4; i++)                                \
        b[i] = *(const bf16x8*)&Bb[(wn + i * 16 + l16) * 8];                     \
    __builtin_amdgcn_s_setprio(1);                                               \
    _Pragma("unroll") for (int i = 0; i < 4; i++)                                \
        _Pragma("unroll") for (int j = 0; j < 4; j++)                            \
            acc[i][j] = __builtin_amdgcn_mfma_f32_16x16x32_bf16(a[i], b[j],      \
                                                                acc[i][j], 0, 0, 0); \
    __builtin_amdgcn_s_setprio(0);                                               \
  } while (0)

  const int nt = K >> 5;  // 16 at both call sites (>= 4 required)
  STAGE(0, 0);
  STAGE(1, 32);
  STAGE(2, 64);
  for (int t = 0; t < nt - 3; ++t) {          // t = 0..nt-4
    VMW(8);                                    // tile t landed; t+1,t+2 in flight
    BAR();
    STAGE((t + 3) & 3, (t + 3) * 32);          // overwrites buffer of tile t-1
    COMPUTE(t & 3);
  }
  VMW(8); BAR(); COMPUTE((nt - 3) & 3);
  VMW(4); BAR(); COMPUTE((nt - 2) & 3);
  VMW(0); BAR(); COMPUTE((nt - 1) & 3);
#undef STAGE
#undef COMPUTE

  if constexpr (OUT_F32) {
    // proj epilogue: direct f32 stores (16 lanes x 4 B = 64 B segments)
#pragma unroll
    for (int i = 0; i < 4; i++) {
      const int row = bm + wm + i * 16 + quad * 4;
#pragma unroll
      for (int j = 0; j < 4; j++) {
        const int col = bn + wn + j * 16 + l16;
        const float bv = bias[col];
#pragma unroll
        for (int r = 0; r < 4; r++)
          ((float*)Cptr)[(size_t)(row + r) * ldc + col] = acc[i][j][r] + bv;
      }
    }
  } else {
    // bf16 epilogue: stage the 128x128 bf16 tile in LDS (As = 32 KB exactly),
    // then store 256 B-coalesced rows (16 lanes x 16 B contiguous).
    unsigned short* Ct = &As[0][0];
    __syncthreads();  // all waves done with As/Bs as staging buffers
#pragma unroll
    for (int i = 0; i < 4; i++) {
#pragma unroll
      for (int j = 0; j < 4; j++) {
        const int colg = bn + wn + j * 16 + l16;
        const float bv = bias[colg];
        const float sc = (colg < scale_cols) ? scale : 1.0f;
        const int coll = wn + j * 16 + l16;
#pragma unroll
        for (int r = 0; r < 4; r++) {
          const int rowl = wm + i * 16 + quad * 4 + r;
          Ct[rowl * 128 + coll] = f2bf((acc[i][j][r] + bv) * sc);
        }
      }
    }
    __syncthreads();
#pragma unroll
    for (int tt = 0; tt < 8; tt++) {
      const int row = tt * 16 + (tid >> 4);
      const int ce = (tid & 15) * 8;
      uint4 vv = *(const uint4*)&Ct[row * 128 + ce];
      *(uint4*)&((unsigned short*)Cptr)[(size_t)(bm + row) * ldc + bn + ce] = vv;
    }
  }
}

// ---- kernel 3: fused window attention, one wave per (window, head) ----
// qkv layout: [M_ROWS][1536] bf16; cols 0..511=Q*scale (head-major), 512..1023=K, 1024..1535=V.
// Output O overwrites this head's Q columns (disjoint across heads -> race-free).
__global__ __launch_bounds__(256) void attn_mfma(
    unsigned short* __restrict__ qkv,
    const float* __restrict__ bias_table,   // [169][16]
    const float* __restrict__ mask) {       // [64][49][49]
  const int PS = 72;  // P row stride (elems): 16B-aligned rows, good bank spread
  const int VS = 64;  // Vt row stride
  __shared__ __align__(16) unsigned short Pl_all[4][64 * 72];  // 36864 B
  __shared__ __align__(16) unsigned short Vt_all[4][32 * 64];  // 16384 B
  const int tid = threadIdx.x;
  const int wid = tid >> 6, lane = tid & 63;
  const int quad = lane >> 4, l16 = lane & 15;
  const int b = blockIdx.x;
  const int h = blockIdx.y * 4 + wid;
  unsigned short* Pl = Pl_all[wid];
  unsigned short* Vt = Vt_all[wid];
  const size_t row0 = (size_t)b * WIN_N;

  // Q (A-operand) and K (B-operand) fragments direct from global:
  // frag element k-dim = quad*8+j is contiguous 16B in memory.
  bf16x8 aq[4], bk[4];
#pragma unroll
  for (int i = 0; i < 4; i++) {
    size_t r = row0 + i * 16 + l16;
    if (r > (size_t)(M_ROWS - 1)) r = M_ROWS - 1;  // clamp: garbage rows only feed t>=49 / m>=49
    const unsigned short* pq = qkv + r * QKV_N + h * HD + quad * 8;
    aq[i] = *(const bf16x8*)pq;
    bk[i] = *(const bf16x8*)(pq + 512);
  }

  // V^T into LDS: Vt[d][m]; zero the m>=49 pad (0 * garbage would NaN otherwise)
  {
    const int m = lane;
    if (m < WIN_N) {
      const unsigned short* pv = qkv + (row0 + m) * QKV_N + 1024 + h * HD;
      uint4 tv[4];
      tv[0] = *(const uint4*)(pv + 0);
      tv[1] = *(const uint4*)(pv + 8);
      tv[2] = *(const uint4*)(pv + 16);
      tv[3] = *(const uint4*)(pv + 24);
      const unsigned short* tmp = (const unsigned short*)tv;
#pragma unroll
      for (int d = 0; d < 32; d++) Vt[d * VS + m] = tmp[d];
    } else {
#pragma unroll
      for (int d = 0; d < 32; d++) Vt[d * VS + m] = 0;
    }
  }

  // S = (Q*scale) K^T : 16 MFMAs
  const f32x4 fzero = {0.f, 0.f, 0.f, 0.f};
  f32x4 s[4][4];
#pragma unroll
  for (int i = 0; i < 4; i++)
#pragma unroll
    for (int j = 0; j < 4; j++)
      s[i][j] = __builtin_amdgcn_mfma_f32_16x16x32_bf16(aq[i], bk[j], fzero, 0, 0, 0);

  // bias + mask + row softmax (rows live on 16 lanes sharing quad; shfl-xor 1/2/4/8)
  const float* mrow = mask + (size_t)(b & 63) * (WIN_N * WIN_N);
#pragma unroll
  for (int i = 0; i < 4; i++) {
#pragma unroll
    for (int r = 0; r < 4; r++) {
      const int t = i * 16 + quad * 4 + r;
      const int ti = t / 7, tj = t % 7;
      float v[4];
#pragma unroll
      for (int j = 0; j < 4; j++) {
        const int m = j * 16 + l16;
        float x = s[i][j][r];
        if (t < WIN_N && m < WIN_N) {
          const int mi = m / 7, mj = m % 7;
          const int idx = (tj - mj + 6) * 13 + (ti - mi + 6);
          x += bias_table[idx * NH + h] + mrow[t * WIN_N + m];
        }
        if (m >= WIN_N) x = -3.0e38f;  // pad cols vanish in softmax
        v[j] = x;
      }
      float mx = fmaxf(fmaxf(v[0], v[1]), fmaxf(v[2], v[3]));
      mx = fmaxf(mx, __shfl_xor(mx, 1));
      mx = fmaxf(mx, __shfl_xor(mx, 2));
      mx = fmaxf(mx, __shfl_xor(mx, 4));
      mx = fmaxf(mx, __shfl_xor(mx, 8));
      float p[4];
      float sum = 0.f;
#pragma unroll
      for (int j = 0; j < 4; j++) {
        p[j] = __expf(v[j] - mx);
        sum += p[j];
      }
      sum += __shfl_xor(sum, 1);
      sum += __shfl_xor(sum, 2);
      sum += __shfl_xor(sum, 4);
      sum += __shfl_xor(sum, 8);
      const float inv = 1.0f / sum;
#pragma unroll
      for (int j = 0; j < 4; j++) Pl[t * PS + j * 16 + l16] = f2bf(p[j] * inv);
    }
  }
  __syncthreads();  // P,Vt (per-wave regions) ordered before frag reads

  // O = P V : P re-read in A-layout from LDS, Vt is the B^T operand
  f32x4 o[4][2];
#pragma unroll
  for (int i = 0; i < 4; i++)
#pragma unroll
    for (int ni = 0; ni < 2; ni++) o[i][ni] = fzero;
#pragma unroll
  for (int ki = 0; ki < 2; ki++) {
    bf16x8 bv[2];
#pragma unroll
    for (int ni = 0; ni < 2; ni++)
      bv[ni] = *(const bf16x8*)&Vt[(ni * 16 + l16) * VS + ki * 32 + quad * 8];
#pragma unroll
    for (int i = 0; i < 4; i++) {
      bf16x8 ap = *(const bf16x8*)&Pl[(i * 16 + l16) * PS + ki * 32 + quad * 8];
#pragma unroll
      for (int ni = 0; ni < 2; ni++)
        o[i][ni] = __builtin_amdgcn_mfma_f32_16x16x32_bf16(ap, bv[ni], o[i][ni], 0, 0, 0);
    }
  }

  // store O into this head's Q columns (bf16), rows t<49 only
#pragma unroll
  for (int i = 0; i < 4; i++) {
#pragma unroll
    for (int r = 0; r < 4; r++) {
      const int t = i * 16 + quad * 4 + r;
      if (t < WIN_N) {
        unsigned short* po = qkv + (row0 + t) * QKV_N + h * HD;
        po[l16] = f2bf(o[i][0][r]);
        po[16 + l16] = f2bf(o[i][1][r]);
      }
    }
  }
}

extern "C" void kernel_launch(void* const* d_in, const int* in_sizes, int n_in,
                              void* d_out, int out_size, void* d_ws, size_t ws_size,
                              hipStream_t stream) {
  const float* x = (const float*)d_in[0];
  const float* mask = (const float*)d_in[1];
  const float* qkv_w = (const float*)d_in[2];
  const float* qkv_b = (const float*)d_in[3];
  const float* proj_w = (const float*)d_in[4];
  const float* proj_b = (const float*)d_in[5];
  const float* bias_table = (const float*)d_in[6];
  float* out = (float*)d_out;

  // workspace: qkv buffer (bf16, doubles as attention output in Q slots) + transposed weights
  unsigned short* qkvb = (unsigned short*)d_ws;                       // 200704*1536*2 = 616562688 B
  unsigned short* wqkv_t = qkvb + (size_t)M_ROWS * QKV_N;             // 1536*512*2
  unsigned short* wproj_t = wqkv_t + (size_t)QKV_N * CDIM;            // 512*512*2  (total ~619 MB)

  // x_bf16 scratch lives in d_out (dead by the time proj writes out)
  unsigned short* xb = (unsigned short*)d_out;

  prep_weights<<<4096, 256, 0, stream>>>(qkv_w, proj_w, wqkv_t, wproj_t);
  conv_x<<<4096, 256, 0, stream>>>(x, xb, (M_ROWS * CDIM) / 8);

  // QKV: [200704x512]bf16 @ [512x1536] -> bf16, scale Q cols, +qkv_b
  gemm_bt<false><<<dim3(QKV_N / 128, M_ROWS / 128), 256, 0, stream>>>(
      xb, CDIM, wqkv_t, qkvb, QKV_N, qkv_b, CDIM, 512, SCALE_Q);

  // fused window attention
  attn_mfma<<<dim3(NB, NH / 4), 256, 0, stream>>>(qkvb, bias_table, mask);

  // proj: [200704x512]bf16 (stride 1536) @ [512x512] -> f32 out, +proj_b
  gemm_bt<true><<<dim3(CDIM / 128, M_ROWS / 128), 256, 0, stream>>>(
      qkvb, QKV_N, wproj_t, out, CDIM, proj_b, CDIM, 0, 1.0f);
}

// Round 4
// 1861.276 us; speedup vs baseline: 1.1455x; 1.1455x over previous
//
#include <hip/hip_runtime.h>
#include <stdint.h>

// ---- problem constants ----
#define WIN_N 49
#define NH 16
#define HD 32
#define CDIM 512
#define NB 4096
#define M_ROWS (NB * WIN_N)        // 200704 = 128 * 1568 exactly
#define QKV_N 1536
#define SCALE_Q 0.17677669529663689f  // 32^-0.5

typedef __attribute__((ext_vector_type(8))) short bf16x8;
typedef __attribute__((ext_vector_type(4))) float f32x4;

__device__ __forceinline__ unsigned short f2bf(float f) {
  unsigned int u = __float_as_uint(f);
  u += 0x7fff + ((u >> 16) & 1);   // RNE
  return (unsigned short)(u >> 16);
}
__device__ __forceinline__ unsigned int pack2(float a, float b) {
  return (unsigned int)f2bf(a) | ((unsigned int)f2bf(b) << 16);
}

// global->LDS direct DMA, 16B/lane. LDS dest is wave-uniform base + lane*16
// (m97/m104 semantics); global src is per-lane.
typedef const __attribute__((address_space(1))) unsigned int* gas1_t;
typedef __attribute__((address_space(3))) unsigned int* las3_t;
#define GL2LDS(g, l) __builtin_amdgcn_global_load_lds((gas1_t)(g), (las3_t)(l), 16, 0, 0)

// counted vmcnt wait (T4): compile-time constant N; "memory" clobber fences
// compiler code-motion of memory ops both directions.
#define VMW(n) asm volatile("s_waitcnt vmcnt(" #n ")" ::: "memory")
// raw barrier: lgkmcnt(0) first (our ds_reads are already MFMA-consumed, so
// ~free) guarantees this wave's LDS reads fully completed before it enters the
// barrier -> post-barrier gl2lds overwrites are race-free. NO sched_barrier
// (m141: order-pinning cost -42%).
#define BAR()                                              \
  do {                                                     \
    asm volatile("s_waitcnt lgkmcnt(0)" ::: "memory");     \
    __builtin_amdgcn_s_barrier();                          \
    asm volatile("" ::: "memory");                         \
  } while (0)

// ---- kernel 1: transpose + bf16-convert weights: wT[n][k] = w[k][n] ----
__global__ void prep_weights(const float* __restrict__ qkv_w,
                             const float* __restrict__ proj_w,
                             unsigned short* __restrict__ wqkv_t,
                             unsigned short* __restrict__ wproj_t) {
  int i = blockIdx.x * blockDim.x + threadIdx.x;
  if (i < QKV_N * CDIM) {                 // 786432: [1536][512]
    int n = i >> 9, k = i & 511;
    wqkv_t[i] = f2bf(qkv_w[k * QKV_N + n]);
  } else {
    int j = i - QKV_N * CDIM;
    if (j < CDIM * CDIM) {                // 262144: [512][512]
      int n = j >> 9, k = j & 511;
      wproj_t[j] = f2bf(proj_w[k * CDIM + n]);
    }
  }
}

// ---- kernel 1b: x (f32) -> xb (bf16), one pass, memory-bound ----
__global__ void conv_x(const float* __restrict__ x,
                       unsigned short* __restrict__ xb, int n8) {
  int i = blockIdx.x * blockDim.x + threadIdx.x;
  const int stride = gridDim.x * blockDim.x;
  for (; i < n8; i += stride) {
    const float4* p = (const float4*)(x + (size_t)i * 8);
    float4 a = p[0], b = p[1];
    *(uint4*)(xb + (size_t)i * 8) =
        make_uint4(pack2(a.x, a.y), pack2(a.z, a.w), pack2(b.x, b.y), pack2(b.z, b.w));
  }
}

// ---- kernel 2/4: C[M][N] = A[M][K] * Bt[N][K]^T, 128x128 tile, BK=32 ----
// Ring-4 counted-vmcnt pipeline (T3+T4): 4 LDS buffers; stage tile t+3 while
// computing t; per-tile sync = VMW(8) + raw barrier -> 8 loads (2 tiles) stay
// in flight across every barrier; drain 8->4->0 only in the 3-iter tail.
//
// LDS layout: row-major [128 rows][4 segs][8 ushort] per buffer, with k-seg
// XOR swizzle f(row) = (row>>1)&3 (rule #21, both sides):
//  - staging thread tid -> linear LDS bytes tid*16 (gl2lds uniform+lane*16),
//    i.e. (row=tid>>2, seg=tid&3); its GLOBAL seg is (tid&3)^((tid>>3)&3),
//    so each 4-tid group still covers one row's full 64B line (coalesced,
//    16 full lines per wave-instruction - same as the 547us R2 staging).
//  - frag read seg = quad ^ ((l16>>1)&3): per 8-lane phase the 32 dwords hit
//    all 32 banks exactly once -> conflict-free ds_read_b128 (vs 4-way in R2).
template <bool OUT_F32>
__global__ __launch_bounds__(256, 2) void gemm_bt(
    const unsigned short* __restrict__ A, int lda,
    const unsigned short* __restrict__ Bt,
    void* __restrict__ Cptr, int ldc,
    const float* __restrict__ bias,
    int K, int scale_cols, float scale) {
  __shared__ __align__(16) unsigned short As[4][4096];  // 4 x 8KB
  __shared__ __align__(16) unsigned short Bs[4][4096];  // 4 x 8KB  (total 64KB)
  const int tid = threadIdx.x;

  // T1: XCD-chunked bijective block swizzle (nwg % 8 == 0 at both call sites).
  const int gx = gridDim.x;
  const int nwg = gx * gridDim.y;
  int lin = blockIdx.y * gx + blockIdx.x;
  lin = (lin & 7) * (nwg >> 3) + (lin >> 3);
  const int bm = (lin / gx) * 128;
  const int bn = (lin % gx) * 128;

  const int lane = tid & 63, wid = tid >> 6;
  const int wm = (wid & 1) * 64, wn = (wid >> 1) * 64;
  const int quad = lane >> 4, l16 = lane & 15;
  const int sRd = quad ^ ((l16 >> 1) & 3);   // swizzled k-seg for frag reads

  const f32x4 fzero = {0.f, 0.f, 0.f, 0.f};
  f32x4 acc[4][4];
#pragma unroll
  for (int i = 0; i < 4; i++)
#pragma unroll
    for (int j = 0; j < 4; j++) acc[i][j] = fzero;

  // staging source: thread tid covers (row rS, global k-seg sS) and rS+64.
  // f(rS) == f(rS+64) since (rS+64)>>1 differs by 32 (multiple of 4).
  const int rS = tid >> 2;
  const int sS = (tid & 3) ^ ((tid >> 3) & 3);
  const unsigned short* pA0 = A + (size_t)(bm + rS) * lda + sS * 8;
  const unsigned short* pB0 = Bt + (size_t)(bn + rS) * K + sS * 8;
  const size_t a64 = (size_t)64 * lda;
  const size_t b64 = (size_t)64 * K;

#define STAGE(bb, kk_)                                     \
  do {                                                     \
    GL2LDS(pA0 + (kk_), &As[bb][wid * 512]);               \
    GL2LDS(pA0 + (kk_) + a64, &As[bb][2048 + wid * 512]);  \
    GL2LDS(pB0 + (kk_), &Bs[bb][wid * 512]);               \
    GL2LDS(pB0 + (kk_) + b64, &Bs[bb][2048 + wid * 512]);  \
  } while (0)

#define COMPUTE(bb)                                                              \
  do {                                                                           \
    bf16x8 a[4], b[4];                                                           \
    _Pragma("unroll") for (int i = 0; i < 4; i++)                                \
        a[i] = *(const bf16x8*)&As[bb][(wm + i * 16 + l16) * 32 + sRd * 8];      \
    _Pragma("unroll") for (int i = 0; i < 4; i++)                                \
        b[i] = *(const bf16x8*)&Bs[bb][(wn + i * 16 + l16) * 32 + sRd * 8];      \
    __builtin_amdgcn_s_setprio(1);                                               \
    _Pragma("unroll") for (int i = 0; i < 4; i++)                                \
        _Pragma("unroll") for (int j = 0; j < 4; j++)                            \
            acc[i][j] = __builtin_amdgcn_mfma_f32_16x16x32_bf16(a[i], b[j],      \
                                                                acc[i][j], 0, 0, 0); \
    __builtin_amdgcn_s_setprio(0);                                               \
  } while (0)

  const int nt = K >> 5;  // 16 at both call sites (>= 4 required)
  STAGE(0, 0);
  STAGE(1, 32);
  STAGE(2, 64);
  for (int t = 0; t < nt - 3; ++t) {          // t = 0..nt-4
    VMW(8);                                    // own tile-t loads landed
    BAR();                                     // => ALL waves' tile-t loads landed
    STAGE((t + 3) & 3, (t + 3) * 32);          // overwrites buffer of tile t-1
    COMPUTE(t & 3);
  }
  VMW(8); BAR(); COMPUTE((nt - 3) & 3);
  VMW(4); BAR(); COMPUTE((nt - 2) & 3);
  VMW(0); BAR(); COMPUTE((nt - 1) & 3);
#undef STAGE
#undef COMPUTE

  if constexpr (OUT_F32) {
    // proj epilogue: direct f32 stores (16 lanes x 4 B = 64 B segments)
#pragma unroll
    for (int i = 0; i < 4; i++) {
      const int row = bm + wm + i * 16 + quad * 4;
#pragma unroll
      for (int j = 0; j < 4; j++) {
        const int col = bn + wn + j * 16 + l16;
        const float bv = bias[col];
#pragma unroll
        for (int r = 0; r < 4; r++)
          ((float*)Cptr)[(size_t)(row + r) * ldc + col] = acc[i][j][r] + bv;
      }
    }
  } else {
    // bf16 epilogue: stage the 128x128 bf16 tile in LDS (As = 32 KB exactly),
    // then store 256 B-coalesced rows (16 lanes x 16 B contiguous).
    unsigned short* Ct = &As[0][0];
    __syncthreads();  // all waves done with As/Bs as staging buffers
#pragma unroll
    for (int i = 0; i < 4; i++) {
#pragma unroll
      for (int j = 0; j < 4; j++) {
        const int colg = bn + wn + j * 16 + l16;
        const float bv = bias[colg];
        const float sc = (colg < scale_cols) ? scale : 1.0f;
        const int coll = wn + j * 16 + l16;
#pragma unroll
        for (int r = 0; r < 4; r++) {
          const int rowl = wm + i * 16 + quad * 4 + r;
          Ct[rowl * 128 + coll] = f2bf((acc[i][j][r] + bv) * sc);
        }
      }
    }
    __syncthreads();
#pragma unroll
    for (int tt = 0; tt < 8; tt++) {
      const int row = tt * 16 + (tid >> 4);
      const int ce = (tid & 15) * 8;
      uint4 vv = *(const uint4*)&Ct[row * 128 + ce];
      *(uint4*)&((unsigned short*)Cptr)[(size_t)(bm + row) * ldc + bn + ce] = vv;
    }
  }
}

// ---- kernel 3: fused window attention, one wave per (window, head) ----
// qkv layout: [M_ROWS][1536] bf16; cols 0..511=Q*scale (head-major), 512..1023=K, 1024..1535=V.
// Output O overwrites this head's Q columns (disjoint across heads -> race-free).
__global__ __launch_bounds__(256) void attn_mfma(
    unsigned short* __restrict__ qkv,
    const float* __restrict__ bias_table,   // [169][16]
    const float* __restrict__ mask) {       // [64][49][49]
  const int PS = 72;  // P row stride (elems): 16B-aligned rows, good bank spread
  const int VS = 64;  // Vt row stride
  __shared__ __align__(16) unsigned short Pl_all[4][64 * 72];  // 36864 B
  __shared__ __align__(16) unsigned short Vt_all[4][32 * 64];  // 16384 B
  const int tid = threadIdx.x;
  const int wid = tid >> 6, lane = tid & 63;
  const int quad = lane >> 4, l16 = lane & 15;
  const int b = blockIdx.x;
  const int h = blockIdx.y * 4 + wid;
  unsigned short* Pl = Pl_all[wid];
  unsigned short* Vt = Vt_all[wid];
  const size_t row0 = (size_t)b * WIN_N;

  // Q (A-operand) and K (B-operand) fragments direct from global:
  // frag element k-dim = quad*8+j is contiguous 16B in memory.
  bf16x8 aq[4], bk[4];
#pragma unroll
  for (int i = 0; i < 4; i++) {
    size_t r = row0 + i * 16 + l16;
    if (r > (size_t)(M_ROWS - 1)) r = M_ROWS - 1;  // clamp: garbage rows only feed t>=49 / m>=49
    const unsigned short* pq = qkv + r * QKV_N + h * HD + quad * 8;
    aq[i] = *(const bf16x8*)pq;
    bk[i] = *(const bf16x8*)(pq + 512);
  }

  // V^T into LDS: Vt[d][m]; zero the m>=49 pad (0 * garbage would NaN otherwise)
  {
    const int m = lane;
    if (m < WIN_N) {
      const unsigned short* pv = qkv + (row0 + m) * QKV_N + 1024 + h * HD;
      uint4 tv[4];
      tv[0] = *(const uint4*)(pv + 0);
      tv[1] = *(const uint4*)(pv + 8);
      tv[2] = *(const uint4*)(pv + 16);
      tv[3] = *(const uint4*)(pv + 24);
      const unsigned short* tmp = (const unsigned short*)tv;
#pragma unroll
      for (int d = 0; d < 32; d++) Vt[d * VS + m] = tmp[d];
    } else {
#pragma unroll
      for (int d = 0; d < 32; d++) Vt[d * VS + m] = 0;
    }
  }

  // S = (Q*scale) K^T : 16 MFMAs
  const f32x4 fzero = {0.f, 0.f, 0.f, 0.f};
  f32x4 s[4][4];
#pragma unroll
  for (int i = 0; i < 4; i++)
#pragma unroll
    for (int j = 0; j < 4; j++)
      s[i][j] = __builtin_amdgcn_mfma_f32_16x16x32_bf16(aq[i], bk[j], fzero, 0, 0, 0);

  // bias + mask + row softmax (rows live on 16 lanes sharing quad; shfl-xor 1/2/4/8)
  const float* mrow = mask + (size_t)(b & 63) * (WIN_N * WIN_N);
#pragma unroll
  for (int i = 0; i < 4; i++) {
#pragma unroll
    for (int r = 0; r < 4; r++) {
      const int t = i * 16 + quad * 4 + r;
      const int ti = t / 7, tj = t % 7;
      float v[4];
#pragma unroll
      for (int j = 0; j < 4; j++) {
        const int m = j * 16 + l16;
        float x = s[i][j][r];
        if (t < WIN_N && m < WIN_N) {
          const int mi = m / 7, mj = m % 7;
          const int idx = (tj - mj + 6) * 13 + (ti - mi + 6);
          x += bias_table[idx * NH + h] + mrow[t * WIN_N + m];
        }
        if (m >= WIN_N) x = -3.0e38f;  // pad cols vanish in softmax
        v[j] = x;
      }
      float mx = fmaxf(fmaxf(v[0], v[1]), fmaxf(v[2], v[3]));
      mx = fmaxf(mx, __shfl_xor(mx, 1));
      mx = fmaxf(mx, __shfl_xor(mx, 2));
      mx = fmaxf(mx, __shfl_xor(mx, 4));
      mx = fmaxf(mx, __shfl_xor(mx, 8));
      float p[4];
      float sum = 0.f;
#pragma unroll
      for (int j = 0; j < 4; j++) {
        p[j] = __expf(v[j] - mx);
        sum += p[j];
      }
      sum += __shfl_xor(sum, 1);
      sum += __shfl_xor(sum, 2);
      sum += __shfl_xor(sum, 4);
      sum += __shfl_xor(sum, 8);
      const float inv = 1.0f / sum;
#pragma unroll
      for (int j = 0; j < 4; j++) Pl[t * PS + j * 16 + l16] = f2bf(p[j] * inv);
    }
  }
  __syncthreads();  // P,Vt (per-wave regions) ordered before frag reads

  // O = P V : P re-read in A-layout from LDS, Vt is the B^T operand
  f32x4 o[4][2];
#pragma unroll
  for (int i = 0; i < 4; i++)
#pragma unroll
    for (int ni = 0; ni < 2; ni++) o[i][ni] = fzero;
#pragma unroll
  for (int ki = 0; ki < 2; ki++) {
    bf16x8 bv[2];
#pragma unroll
    for (int ni = 0; ni < 2; ni++)
      bv[ni] = *(const bf16x8*)&Vt[(ni * 16 + l16) * VS + ki * 32 + quad * 8];
#pragma unroll
    for (int i = 0; i < 4; i++) {
      bf16x8 ap = *(const bf16x8*)&Pl[(i * 16 + l16) * PS + ki * 32 + quad * 8];
#pragma unroll
      for (int ni = 0; ni < 2; ni++)
        o[i][ni] = __builtin_amdgcn_mfma_f32_16x16x32_bf16(ap, bv[ni], o[i][ni], 0, 0, 0);
    }
  }

  // store O into this head's Q columns (bf16), rows t<49 only
#pragma unroll
  for (int i = 0; i < 4; i++) {
#pragma unroll
    for (int r = 0; r < 4; r++) {
      const int t = i * 16 + quad * 4 + r;
      if (t < WIN_N) {
        unsigned short* po = qkv + (row0 + t) * QKV_N + h * HD;
        po[l16] = f2bf(o[i][0][r]);
        po[16 + l16] = f2bf(o[i][1][r]);
      }
    }
  }
}

extern "C" void kernel_launch(void* const* d_in, const int* in_sizes, int n_in,
                              void* d_out, int out_size, void* d_ws, size_t ws_size,
                              hipStream_t stream) {
  const float* x = (const float*)d_in[0];
  const float* mask = (const float*)d_in[1];
  const float* qkv_w = (const float*)d_in[2];
  const float* qkv_b = (const float*)d_in[3];
  const float* proj_w = (const float*)d_in[4];
  const float* proj_b = (const float*)d_in[5];
  const float* bias_table = (const float*)d_in[6];
  float* out = (float*)d_out;

  // workspace: qkv buffer (bf16, doubles as attention output in Q slots) + transposed weights
  unsigned short* qkvb = (unsigned short*)d_ws;                       // 200704*1536*2 = 616562688 B
  unsigned short* wqkv_t = qkvb + (size_t)M_ROWS * QKV_N;             // 1536*512*2
  unsigned short* wproj_t = wqkv_t + (size_t)QKV_N * CDIM;            // 512*512*2  (total ~619 MB)

  // x_bf16 scratch lives in d_out (dead by the time proj writes out)
  unsigned short* xb = (unsigned short*)d_out;

  prep_weights<<<4096, 256, 0, stream>>>(qkv_w, proj_w, wqkv_t, wproj_t);
  conv_x<<<4096, 256, 0, stream>>>(x, xb, (M_ROWS * CDIM) / 8);

  // QKV: [200704x512]bf16 @ [512x1536] -> bf16, scale Q cols, +qkv_b
  gemm_bt<false><<<dim3(QKV_N / 128, M_ROWS / 128), 256, 0, stream>>>(
      xb, CDIM, wqkv_t, qkvb, QKV_N, qkv_b, CDIM, 512, SCALE_Q);

  // fused window attention
  attn_mfma<<<dim3(NB, NH / 4), 256, 0, stream>>>(qkvb, bias_table, mask);

  // proj: [200704x512]bf16 (stride 1536) @ [512x512] -> f32 out, +proj_b
  gemm_bt<true><<<dim3(CDIM / 128, M_ROWS / 128), 256, 0, stream>>>(
      qkvb, QKV_N, wproj_t, out, CDIM, proj_b, CDIM, 0, 1.0f);
}